// Round 2
// baseline (759.368 us; speedup 1.0000x reference)
//
#include <hip/hip_runtime.h>

// f32 I/O. K=8 expert AEs, B=8192, D=1024, H=256.
//   h = relu(x @ W1[k] + b1[k]); recon = h @ W2[k] + b2[k]
//   err[k,b] = mean((recon-x)^2); out[b] = recon[argmin_k err, b]
// Precision: err must match np-f32 argmin -> split-bf16 (hi/lo) 3-product GEMMs
// for pass1. Winner recon (pass2) only needs 2% abs -> plain bf16-hi GEMMs.
// ws: w1t_hi/lo [k][h][d], w2t_hi/lo [k][d][h] (4 MB each), err, bucket, cnt.

#define KE 8
#define NB 8192
#define ND 1024
#define NH 256
#define BK 32

typedef float f32x4 __attribute__((ext_vector_type(4)));
typedef short s16x8 __attribute__((ext_vector_type(8)));
typedef unsigned short u16x8 __attribute__((ext_vector_type(8)));
typedef unsigned short u16x4 __attribute__((ext_vector_type(4)));

__device__ __forceinline__ float bf2f(unsigned short h) {
  union { unsigned int u; float f; } v; v.u = ((unsigned int)h) << 16; return v.f;
}
__device__ __forceinline__ unsigned short f2bf(float f) {
  union { unsigned int u; float f; } v; v.f = f;
  unsigned int u = v.u;
  u += 0x7fffu + ((u >> 16) & 1u);   // RTNE
  return (unsigned short)(u >> 16);
}
__device__ __forceinline__ void split2(float x, unsigned short& hi, unsigned short& lo) {
  hi = f2bf(x);
  lo = f2bf(x - bf2f(hi));
}

// ---- W1[k][d][h] f32 -> w1t_hi/lo[k][h][d] bf16
__global__ __launch_bounds__(256) void split_w1(const float* __restrict__ in,
                                                unsigned short* __restrict__ oh,
                                                unsigned short* __restrict__ ol) {
  int g = blockIdx.x * 256 + threadIdx.x;   // K*NH*(ND/8) = 262144
  int k = g >> 15;
  int r = g & 32767;
  int j = r & (NH - 1);                      // lanes consecutive in j -> coalesced
  int d8 = (r >> 8) * 8;
  unsigned short th[8], tl[8];
#pragma unroll
  for (int q = 0; q < 8; ++q) {
    float v = in[((size_t)k * ND + d8 + q) * NH + j];
    split2(v, th[q], tl[q]);
  }
  size_t o = ((size_t)k * NH + j) * ND + d8;
  *(u16x8*)&oh[o] = *(u16x8*)th;
  *(u16x8*)&ol[o] = *(u16x8*)tl;
}

// ---- W2[k][h][d] f32 -> w2t_hi/lo[k][d][h] bf16
__global__ __launch_bounds__(256) void split_w2(const float* __restrict__ in,
                                                unsigned short* __restrict__ oh,
                                                unsigned short* __restrict__ ol) {
  int g = blockIdx.x * 256 + threadIdx.x;
  int k = g >> 15;
  int r = g & 32767;
  int d = r & (ND - 1);                      // lanes consecutive in d -> coalesced
  int h8 = (r >> 10) * 8;
  unsigned short th[8], tl[8];
#pragma unroll
  for (int q = 0; q < 8; ++q) {
    float v = in[((size_t)k * NH + h8 + q) * ND + d];
    split2(v, th[q], tl[q]);
  }
  size_t o = ((size_t)k * ND + d) * NH + h8;
  *(u16x8*)&oh[o] = *(u16x8*)th;
  *(u16x8*)&ol[o] = *(u16x8*)tl;
}

// ---- pass 1: split-precision err[K][B]. BM=32 rows/block, grid (256, KE).
__global__ __launch_bounds__(256) void ae_pass1(
    const float* __restrict__ x,
    const unsigned short* __restrict__ w1h, const unsigned short* __restrict__ w1l,
    const float* __restrict__ b1,
    const unsigned short* __restrict__ w2h, const unsigned short* __restrict__ w2l,
    const float* __restrict__ b2, float* __restrict__ err) {
  __shared__ unsigned short xs_h[32][BK + 8], xs_l[32][BK + 8];   // 5120 B
  __shared__ unsigned short hs_h[32][NH + 8], hs_l[32][NH + 8];   // 33792 B
  __shared__ float xc[32][68];                                     // 8704 B
  __shared__ float errp[4][32];                                    // 512 B

  const int tid = threadIdx.x;
  const int wv = tid >> 6;
  const int lane = tid & 63;
  const int lo = lane & 15;
  const int quad = lane >> 4;
  const int k = blockIdx.y;
  const int r0 = blockIdx.x * 32;

  // ---------- phase A: h = relu(x@W1+b1), M=32, N=256 (wave: 64 cols), Kd=1024
  f32x4 acc1[2][4];
#pragma unroll
  for (int mt = 0; mt < 2; ++mt)
#pragma unroll
    for (int nt = 0; nt < 4; ++nt) acc1[mt][nt] = (f32x4){0.f, 0.f, 0.f, 0.f};

  const int lrow = tid >> 3, lcol = (tid & 7) * 4;
  for (int kk = 0; kk < ND; kk += BK) {
    float4 xv = *(const float4*)&x[(size_t)(r0 + lrow) * ND + kk + lcol];
    __syncthreads();   // previous iter's fragment reads done
    unsigned short th[4], tl[4];
    split2(xv.x, th[0], tl[0]); split2(xv.y, th[1], tl[1]);
    split2(xv.z, th[2], tl[2]); split2(xv.w, th[3], tl[3]);
    *(u16x4*)&xs_h[lrow][lcol] = *(u16x4*)th;
    *(u16x4*)&xs_l[lrow][lcol] = *(u16x4*)tl;
    __syncthreads();

    s16x8 ah[2], al[2];
#pragma unroll
    for (int mt = 0; mt < 2; ++mt) {
      ah[mt] = *(const s16x8*)&xs_h[mt * 16 + lo][quad * 8];
      al[mt] = *(const s16x8*)&xs_l[mt * 16 + lo][quad * 8];
    }
#pragma unroll
    for (int nt = 0; nt < 4; ++nt) {
      size_t wo = ((size_t)k * NH + wv * 64 + nt * 16 + lo) * ND + kk + quad * 8;
      s16x8 bh = *(const s16x8*)&w1h[wo];
      s16x8 bl = *(const s16x8*)&w1l[wo];
#pragma unroll
      for (int mt = 0; mt < 2; ++mt) {
        acc1[mt][nt] = __builtin_amdgcn_mfma_f32_16x16x32_bf16(ah[mt], bh, acc1[mt][nt], 0, 0, 0);
        acc1[mt][nt] = __builtin_amdgcn_mfma_f32_16x16x32_bf16(ah[mt], bl, acc1[mt][nt], 0, 0, 0);
        acc1[mt][nt] = __builtin_amdgcn_mfma_f32_16x16x32_bf16(al[mt], bh, acc1[mt][nt], 0, 0, 0);
      }
    }
  }
  __syncthreads();

  // epilogue A: +b1, relu, split h -> LDS (C/D: col=lo, row=quad*4+i)
#pragma unroll
  for (int nt = 0; nt < 4; ++nt) {
    float b1v = b1[(size_t)k * NH + wv * 64 + nt * 16 + lo];
#pragma unroll
    for (int mt = 0; mt < 2; ++mt)
#pragma unroll
      for (int i = 0; i < 4; ++i) {
        float v = acc1[mt][nt][i] + b1v;
        v = v > 0.f ? v : 0.f;
        unsigned short vh, vl;
        split2(v, vh, vl);
        int row = mt * 16 + quad * 4 + i, col = wv * 64 + nt * 16 + lo;
        hs_h[row][col] = vh;
        hs_l[row][col] = vl;
      }
  }
  __syncthreads();

  // ---------- phase B: recon = h@W2+b2 in 64-wide d2 chunks; wave wv owns 16 cols
  float eacc[2][4];
#pragma unroll
  for (int mt = 0; mt < 2; ++mt)
#pragma unroll
    for (int i = 0; i < 4; ++i) eacc[mt][i] = 0.f;

  const int crow = tid >> 3, ccol = (tid & 7) * 8;
  for (int c = 0; c < ND / 64; ++c) {
    float4 xa = *(const float4*)&x[(size_t)(r0 + crow) * ND + c * 64 + ccol];
    float4 xb = *(const float4*)&x[(size_t)(r0 + crow) * ND + c * 64 + ccol + 4];
    *(float4*)&xc[crow][ccol] = xa;
    *(float4*)&xc[crow][ccol + 4] = xb;
    __syncthreads();

    const int d2 = c * 64 + wv * 16 + lo;
    f32x4 acc2[2];
    acc2[0] = (f32x4){0.f, 0.f, 0.f, 0.f};
    acc2[1] = (f32x4){0.f, 0.f, 0.f, 0.f};
#pragma unroll
    for (int kc = 0; kc < NH; kc += 32) {
      s16x8 ah[2], al[2];
#pragma unroll
      for (int mt = 0; mt < 2; ++mt) {
        ah[mt] = *(const s16x8*)&hs_h[mt * 16 + lo][kc + quad * 8];
        al[mt] = *(const s16x8*)&hs_l[mt * 16 + lo][kc + quad * 8];
      }
      size_t wo = ((size_t)k * ND + d2) * NH + kc + quad * 8;
      s16x8 bh = *(const s16x8*)&w2h[wo];
      s16x8 bl = *(const s16x8*)&w2l[wo];
#pragma unroll
      for (int mt = 0; mt < 2; ++mt) {
        acc2[mt] = __builtin_amdgcn_mfma_f32_16x16x32_bf16(ah[mt], bh, acc2[mt], 0, 0, 0);
        acc2[mt] = __builtin_amdgcn_mfma_f32_16x16x32_bf16(ah[mt], bl, acc2[mt], 0, 0, 0);
        acc2[mt] = __builtin_amdgcn_mfma_f32_16x16x32_bf16(al[mt], bh, acc2[mt], 0, 0, 0);
      }
    }
    float b2v = b2[(size_t)k * ND + d2];
#pragma unroll
    for (int mt = 0; mt < 2; ++mt)
#pragma unroll
      for (int i = 0; i < 4; ++i) {
        int row = mt * 16 + quad * 4 + i;
        float rec = acc2[mt][i] + b2v;
        float dd = rec - xc[row][wv * 16 + lo];
        eacc[mt][i] += dd * dd;
      }
    __syncthreads();   // xc reads done before next chunk overwrites
  }

  // reduce across the 16 col-lanes, then across waves
#pragma unroll
  for (int mt = 0; mt < 2; ++mt)
#pragma unroll
    for (int i = 0; i < 4; ++i) {
      float v = eacc[mt][i];
      v += __shfl_xor(v, 1, 16);
      v += __shfl_xor(v, 2, 16);
      v += __shfl_xor(v, 4, 16);
      v += __shfl_xor(v, 8, 16);
      if (lo == 0) errp[wv][mt * 16 + quad * 4 + i] = v;
    }
  __syncthreads();
  if (tid < 32)
    err[(size_t)k * NB + r0 + tid] =
        (errp[0][tid] + errp[1][tid] + errp[2][tid] + errp[3][tid]) * (1.0f / (float)ND);
}

// ---- argmin + bucket rows per expert
__global__ __launch_bounds__(256) void ae_argmin(const float* __restrict__ err,
                                                 unsigned int* __restrict__ cnt,
                                                 int* __restrict__ bucket) {
  __shared__ unsigned int lc[KE];
  __shared__ unsigned int base[KE];
  int tid = threadIdx.x;
  if (tid < KE) lc[tid] = 0;
  __syncthreads();
  int b = blockIdx.x * 256 + tid;
  float best = err[b];
  int kmin = 0;
#pragma unroll
  for (int j = 1; j < KE; ++j) {
    float e = err[(size_t)j * NB + b];
    if (e < best) { best = e; kmin = j; }   // strict < == first-min (jnp.argmin)
  }
  unsigned int lpos = atomicAdd(&lc[kmin], 1u);
  __syncthreads();
  if (tid < KE) base[tid] = atomicAdd(&cnt[tid], lc[tid]);
  __syncthreads();
  bucket[(size_t)kmin * NB + (int)(base[kmin] + lpos)] = b;
}

// ---- pass 2: recompute winner rows (plain bf16-hi), write f32 out
__global__ __launch_bounds__(256) void ae_pass2(
    const float* __restrict__ x,
    const unsigned short* __restrict__ w1h, const float* __restrict__ b1,
    const unsigned short* __restrict__ w2h, const float* __restrict__ b2,
    const unsigned int* __restrict__ cnt, const int* __restrict__ bucket,
    float* __restrict__ out) {
  __shared__ unsigned short hs[64][NH + 8];                  // 33792 B
  __shared__ union {
    struct { unsigned short xs[64][BK + 8]; unsigned short w1s[NH][BK + 8]; } a;  // 25600
    struct { unsigned short w2ts[32][NH + 8]; } b;           // 16896
  } u;
  __shared__ int rid[64];

  const int k = blockIdx.y;
  const int cv = (int)cnt[k];
  const int t0 = blockIdx.x * 64;
  if (t0 >= cv) return;                     // uniform exit before any barrier
  const int nrows = min(64, cv - t0);

  const int tid = threadIdx.x;
  const int wv = tid >> 6;
  const int lane = tid & 63;
  const int lo = lane & 15;
  const int quad = lane >> 4;
  const int srow = tid >> 2, scol = (tid & 3) * 8;

  if (tid < 64) {
    int idx = t0 + tid;
    rid[tid] = bucket[(size_t)k * NB + (idx < cv ? idx : t0)];
  }
  __syncthreads();
  const int grow = rid[srow];

  f32x4 acc1[4][4];
#pragma unroll
  for (int mt = 0; mt < 4; ++mt)
#pragma unroll
    for (int nt = 0; nt < 4; ++nt) acc1[mt][nt] = (f32x4){0.f, 0.f, 0.f, 0.f};

  for (int kk = 0; kk < ND; kk += BK) {
    float4 xa = *(const float4*)&x[(size_t)grow * ND + kk + scol];
    float4 xb = *(const float4*)&x[(size_t)grow * ND + kk + scol + 4];
    __syncthreads();
    unsigned short t[8];
    t[0] = f2bf(xa.x); t[1] = f2bf(xa.y); t[2] = f2bf(xa.z); t[3] = f2bf(xa.w);
    t[4] = f2bf(xb.x); t[5] = f2bf(xb.y); t[6] = f2bf(xb.z); t[7] = f2bf(xb.w);
    *(u16x8*)&u.a.xs[srow][scol] = *(u16x8*)t;
#pragma unroll
    for (int p = 0; p < 4; ++p) {
      int j = p * 64 + srow;
      *(u16x8*)&u.a.w1s[j][scol] = *(const u16x8*)&w1h[((size_t)k * NH + j) * ND + kk + scol];
    }
    __syncthreads();
    s16x8 af[4], bfr[4];
#pragma unroll
    for (int mt = 0; mt < 4; ++mt) af[mt] = *(const s16x8*)&u.a.xs[mt * 16 + lo][quad * 8];
#pragma unroll
    for (int nt = 0; nt < 4; ++nt)
      bfr[nt] = *(const s16x8*)&u.a.w1s[wv * 64 + nt * 16 + lo][quad * 8];
#pragma unroll
    for (int mt = 0; mt < 4; ++mt)
#pragma unroll
      for (int nt = 0; nt < 4; ++nt)
        acc1[mt][nt] = __builtin_amdgcn_mfma_f32_16x16x32_bf16(af[mt], bfr[nt], acc1[mt][nt], 0, 0, 0);
  }
  __syncthreads();

#pragma unroll
  for (int nt = 0; nt < 4; ++nt) {
    float b1v = b1[(size_t)k * NH + wv * 64 + nt * 16 + lo];
#pragma unroll
    for (int mt = 0; mt < 4; ++mt)
#pragma unroll
      for (int i = 0; i < 4; ++i) {
        float v = acc1[mt][nt][i] + b1v;
        v = v > 0.f ? v : 0.f;
        hs[mt * 16 + quad * 4 + i][wv * 64 + nt * 16 + lo] = f2bf(v);
      }
  }
  __syncthreads();

  for (int c = 0; c < ND / 32; ++c) {
    const int d2b = c * 32;
#pragma unroll
    for (int p = 0; p < 4; ++p) {
      int d2 = p * 8 + (tid >> 5);
      int jc = (tid & 31) * 8;
      *(u16x8*)&u.b.w2ts[d2][jc] = *(const u16x8*)&w2h[((size_t)k * ND + d2b + d2) * NH + jc];
    }
    __syncthreads();

    f32x4 acc2[2];
    acc2[0] = (f32x4){0.f, 0.f, 0.f, 0.f};
    acc2[1] = (f32x4){0.f, 0.f, 0.f, 0.f};
#pragma unroll
    for (int kc = 0; kc < NH; kc += 32) {
      s16x8 af = *(const s16x8*)&hs[wv * 16 + lo][kc + quad * 8];
#pragma unroll
      for (int nt = 0; nt < 2; ++nt) {
        s16x8 bfr = *(const s16x8*)&u.b.w2ts[nt * 16 + lo][kc + quad * 8];
        acc2[nt] = __builtin_amdgcn_mfma_f32_16x16x32_bf16(af, bfr, acc2[nt], 0, 0, 0);
      }
    }
#pragma unroll
    for (int nt = 0; nt < 2; ++nt) {
      float b2v = b2[(size_t)k * ND + d2b + nt * 16 + lo];
#pragma unroll
      for (int i = 0; i < 4; ++i) {
        int row = wv * 16 + quad * 4 + i;
        if (row < nrows)
          out[(size_t)rid[row] * ND + d2b + nt * 16 + lo] = acc2[nt][i] + b2v;
      }
    }
    __syncthreads();
  }
}

extern "C" void kernel_launch(void* const* d_in, const int* in_sizes, int n_in,
                              void* d_out, int out_size, void* d_ws, size_t ws_size,
                              hipStream_t stream) {
  (void)in_sizes; (void)n_in; (void)out_size; (void)ws_size;
  const float* x  = (const float*)d_in[0];
  const float* W1 = (const float*)d_in[1];
  const float* b1 = (const float*)d_in[2];
  const float* W2 = (const float*)d_in[3];
  const float* b2 = (const float*)d_in[4];
  float* out = (float*)d_out;

  char* ws = (char*)d_ws;
  const size_t szW = (size_t)KE * ND * NH * sizeof(unsigned short);  // 4 MB
  unsigned short* w1h = (unsigned short*)(ws);
  unsigned short* w1l = (unsigned short*)(ws + szW);
  unsigned short* w2h = (unsigned short*)(ws + 2 * szW);
  unsigned short* w2l = (unsigned short*)(ws + 3 * szW);
  float* err          = (float*)(ws + 4 * szW);
  int* bucket         = (int*)(ws + 4 * szW + (size_t)KE * NB * sizeof(float));
  unsigned int* cnt   = (unsigned int*)(ws + 4 * szW + (size_t)KE * NB * sizeof(float)
                                        + (size_t)KE * NB * sizeof(int));
  // ws use ~17.3 MB

  split_w1<<<1024, 256, 0, stream>>>(W1, w1h, w1l);
  split_w2<<<1024, 256, 0, stream>>>(W2, w2h, w2l);
  ae_pass1<<<dim3(NB / 32, KE), 256, 0, stream>>>(x, w1h, w1l, b1, w2h, w2l, b2, err);
  hipMemsetAsync(cnt, 0, KE * sizeof(unsigned int), stream);
  ae_argmin<<<NB / 256, 256, 0, stream>>>(err, cnt, bucket);
  ae_pass2<<<dim3(NB / 64, KE), 256, 0, stream>>>(x, w1h, b1, w2h, b2, cnt, bucket, out);
}

// Round 3
// 725.742 us; speedup vs baseline: 1.0463x; 1.0463x over previous
//
#include <hip/hip_runtime.h>

// f32 I/O. K=8 expert AEs, B=8192, D=1024, H=256.
//   h = relu(x @ W1[k] + b1[k]); recon = h @ W2[k] + b2[k]
//   err[k,b] = mean((recon-x)^2); out[b] = recon[argmin_k err, b]
// Precision (validated R2, absmax 0.0156): pass1 err via split-bf16 hi/lo
// 3-product GEMMs; pass2 winner recon plain bf16-hi.
// R3 changes: expert = blockIdx.x & 7 (XCD pinning -> W L2-resident),
// conflict-free LDS strides (hs 260, xs 36 u16; b64 frag reads),
// phase-B chunk width 128 (2 N-tiles/wave), phase-A single-barrier dbuf.

#define KE 8
#define NB 8192
#define ND 1024
#define NH 256
#define BK 32

typedef float f32x4 __attribute__((ext_vector_type(4)));
typedef short s16x8 __attribute__((ext_vector_type(8)));
typedef unsigned short u16x8 __attribute__((ext_vector_type(8)));
typedef unsigned short u16x4 __attribute__((ext_vector_type(4)));

__device__ __forceinline__ float bf2f(unsigned short h) {
  union { unsigned int u; float f; } v; v.u = ((unsigned int)h) << 16; return v.f;
}
__device__ __forceinline__ unsigned short f2bf(float f) {
  union { unsigned int u; float f; } v; v.f = f;
  unsigned int u = v.u;
  u += 0x7fffu + ((u >> 16) & 1u);   // RTNE
  return (unsigned short)(u >> 16);
}
__device__ __forceinline__ void split2(float x, unsigned short& hi, unsigned short& lo) {
  hi = f2bf(x);
  lo = f2bf(x - bf2f(hi));
}
// two 8B LDS reads (8B-aligned rows; keeps ds_read_b64, conflict-free strides)
__device__ __forceinline__ s16x8 rd8(const unsigned short* p) {
  u16x4 a = *(const u16x4*)p;
  u16x4 b = *(const u16x4*)(p + 4);
  s16x8 r;
  r[0] = a[0]; r[1] = a[1]; r[2] = a[2]; r[3] = a[3];
  r[4] = b[0]; r[5] = b[1]; r[6] = b[2]; r[7] = b[3];
  return r;
}

// ---- W1[k][d][h] f32 -> w1t_hi/lo[k][h][d] bf16
__global__ __launch_bounds__(256) void split_w1(const float* __restrict__ in,
                                                unsigned short* __restrict__ oh,
                                                unsigned short* __restrict__ ol) {
  int g = blockIdx.x * 256 + threadIdx.x;   // K*NH*(ND/8) = 262144
  int k = g >> 15;
  int r = g & 32767;
  int j = r & (NH - 1);
  int d8 = (r >> 8) * 8;
  unsigned short th[8], tl[8];
#pragma unroll
  for (int q = 0; q < 8; ++q) {
    float v = in[((size_t)k * ND + d8 + q) * NH + j];
    split2(v, th[q], tl[q]);
  }
  size_t o = ((size_t)k * NH + j) * ND + d8;
  *(u16x8*)&oh[o] = *(u16x8*)th;
  *(u16x8*)&ol[o] = *(u16x8*)tl;
}

// ---- W2[k][h][d] f32 -> w2t_hi/lo[k][d][h] bf16
__global__ __launch_bounds__(256) void split_w2(const float* __restrict__ in,
                                                unsigned short* __restrict__ oh,
                                                unsigned short* __restrict__ ol) {
  int g = blockIdx.x * 256 + threadIdx.x;
  int k = g >> 15;
  int r = g & 32767;
  int d = r & (ND - 1);
  int h8 = (r >> 10) * 8;
  unsigned short th[8], tl[8];
#pragma unroll
  for (int q = 0; q < 8; ++q) {
    float v = in[((size_t)k * NH + h8 + q) * ND + d];
    split2(v, th[q], tl[q]);
  }
  size_t o = ((size_t)k * ND + d) * NH + h8;
  *(u16x8*)&oh[o] = *(u16x8*)th;
  *(u16x8*)&ol[o] = *(u16x8*)tl;
}

// ---- pass 1: split-precision err[K][B]. 32 rows/block, 1D grid 2048,
// expert = bx & 7 (XCD pinning), row tile = bx >> 3.
__global__ __launch_bounds__(256) void ae_pass1(
    const float* __restrict__ x,
    const unsigned short* __restrict__ w1h, const unsigned short* __restrict__ w1l,
    const float* __restrict__ b1,
    const unsigned short* __restrict__ w2h, const unsigned short* __restrict__ w2l,
    const float* __restrict__ b2, float* __restrict__ err) {
  __shared__ union {
    struct { unsigned short h[2][32][36], l[2][32][36]; } xs;   // 9216 B (phase A, dbuf)
    struct { float xc[32][132]; } bx;                           // 16896 B (phase B)
  } u;
  __shared__ unsigned short hs_h[32][260], hs_l[32][260];       // 33280 B
  __shared__ float errp[4][32];                                  // 512 B

  const int tid = threadIdx.x;
  const int wv = tid >> 6;
  const int lane = tid & 63;
  const int lo = lane & 15;
  const int quad = lane >> 4;
  const int k = blockIdx.x & 7;
  const int r0 = (blockIdx.x >> 3) * 32;

  // ---------- phase A: h = relu(x@W1+b1), M=32, N=256 (wave: 64 cols), Kd=1024
  f32x4 acc1[2][4];
#pragma unroll
  for (int mt = 0; mt < 2; ++mt)
#pragma unroll
    for (int nt = 0; nt < 4; ++nt) acc1[mt][nt] = (f32x4){0.f, 0.f, 0.f, 0.f};

  const int lrow = tid >> 3, lcol = (tid & 7) * 4;
  float4 xv = *(const float4*)&x[(size_t)(r0 + lrow) * ND + lcol];

  for (int it = 0; it < ND / BK; ++it) {
    const int kk = it * BK;
    const int pb = it & 1;

    // W1 B-fragments for this step (global, L2-resident after pinning)
    s16x8 bh[4], bl[4];
#pragma unroll
    for (int nt = 0; nt < 4; ++nt) {
      size_t wo = ((size_t)k * NH + wv * 64 + nt * 16 + lo) * ND + kk + quad * 8;
      bh[nt] = *(const s16x8*)&w1h[wo];
      bl[nt] = *(const s16x8*)&w1l[wo];
    }

    // split current x chunk into dbuf
    unsigned short th[4], tl[4];
    split2(xv.x, th[0], tl[0]); split2(xv.y, th[1], tl[1]);
    split2(xv.z, th[2], tl[2]); split2(xv.w, th[3], tl[3]);
    *(u16x4*)&u.xs.h[pb][lrow][lcol] = *(u16x4*)th;
    *(u16x4*)&u.xs.l[pb][lrow][lcol] = *(u16x4*)tl;

    // prefetch next x chunk
    int kk2 = (it < ND / BK - 1) ? kk + BK : 0;
    float4 xnext = *(const float4*)&x[(size_t)(r0 + lrow) * ND + kk2 + lcol];

    __syncthreads();

    s16x8 ah[2], al[2];
#pragma unroll
    for (int mt = 0; mt < 2; ++mt) {
      ah[mt] = rd8(&u.xs.h[pb][mt * 16 + lo][quad * 8]);
      al[mt] = rd8(&u.xs.l[pb][mt * 16 + lo][quad * 8]);
    }
#pragma unroll
    for (int nt = 0; nt < 4; ++nt)
#pragma unroll
      for (int mt = 0; mt < 2; ++mt) {
        acc1[mt][nt] = __builtin_amdgcn_mfma_f32_16x16x32_bf16(ah[mt], bh[nt], acc1[mt][nt], 0, 0, 0);
        acc1[mt][nt] = __builtin_amdgcn_mfma_f32_16x16x32_bf16(ah[mt], bl[nt], acc1[mt][nt], 0, 0, 0);
        acc1[mt][nt] = __builtin_amdgcn_mfma_f32_16x16x32_bf16(al[mt], bh[nt], acc1[mt][nt], 0, 0, 0);
      }
    xv = xnext;
  }

  // epilogue A: +b1, relu, split h -> LDS (C/D: col=lo, row=quad*4+i)
#pragma unroll
  for (int nt = 0; nt < 4; ++nt) {
    float b1v = b1[(size_t)k * NH + wv * 64 + nt * 16 + lo];
#pragma unroll
    for (int mt = 0; mt < 2; ++mt)
#pragma unroll
      for (int i = 0; i < 4; ++i) {
        float v = acc1[mt][nt][i] + b1v;
        v = v > 0.f ? v : 0.f;
        unsigned short vh, vl;
        split2(v, vh, vl);
        int row = mt * 16 + quad * 4 + i, col = wv * 64 + nt * 16 + lo;
        hs_h[row][col] = vh;
        hs_l[row][col] = vl;
      }
  }
  __syncthreads();

  // ---------- phase B: recon = h@W2+b2, 128-wide d2 chunks; wave: 32 cols (2 nt)
  float eacc[2][4];
#pragma unroll
  for (int mt = 0; mt < 2; ++mt)
#pragma unroll
    for (int i = 0; i < 4; ++i) eacc[mt][i] = 0.f;

  const int crow = tid >> 3, cb = (tid & 7) * 16;
  for (int c = 0; c < ND / 128; ++c) {
    const int d2b = c * 128;
    float4 xl[4];
#pragma unroll
    for (int q = 0; q < 4; ++q)
      xl[q] = *(const float4*)&x[(size_t)(r0 + crow) * ND + d2b + cb + q * 4];
    __syncthreads();   // prev chunk's xc reads done
#pragma unroll
    for (int q = 0; q < 4; ++q) *(float4*)&u.bx.xc[crow][cb + q * 4] = xl[q];
    __syncthreads();

    f32x4 acc2[2][2];
#pragma unroll
    for (int mt = 0; mt < 2; ++mt)
#pragma unroll
      for (int nt = 0; nt < 2; ++nt) acc2[mt][nt] = (f32x4){0.f, 0.f, 0.f, 0.f};

#pragma unroll
    for (int kc = 0; kc < NH; kc += 32) {
      s16x8 ah[2], al[2];
#pragma unroll
      for (int mt = 0; mt < 2; ++mt) {
        ah[mt] = rd8(&hs_h[mt * 16 + lo][kc + quad * 8]);
        al[mt] = rd8(&hs_l[mt * 16 + lo][kc + quad * 8]);
      }
#pragma unroll
      for (int nt = 0; nt < 2; ++nt) {
        size_t wo = ((size_t)k * ND + d2b + wv * 32 + nt * 16 + lo) * NH + kc + quad * 8;
        s16x8 bh = *(const s16x8*)&w2h[wo];
        s16x8 bl = *(const s16x8*)&w2l[wo];
#pragma unroll
        for (int mt = 0; mt < 2; ++mt) {
          acc2[mt][nt] = __builtin_amdgcn_mfma_f32_16x16x32_bf16(ah[mt], bh, acc2[mt][nt], 0, 0, 0);
          acc2[mt][nt] = __builtin_amdgcn_mfma_f32_16x16x32_bf16(ah[mt], bl, acc2[mt][nt], 0, 0, 0);
          acc2[mt][nt] = __builtin_amdgcn_mfma_f32_16x16x32_bf16(al[mt], bh, acc2[mt][nt], 0, 0, 0);
        }
      }
    }
#pragma unroll
    for (int nt = 0; nt < 2; ++nt) {
      float b2v = b2[(size_t)k * ND + d2b + wv * 32 + nt * 16 + lo];
#pragma unroll
      for (int mt = 0; mt < 2; ++mt)
#pragma unroll
        for (int i = 0; i < 4; ++i) {
          int row = mt * 16 + quad * 4 + i;
          float rec = acc2[mt][nt][i] + b2v;
          float dd = rec - u.bx.xc[row][wv * 32 + nt * 16 + lo];
          eacc[mt][i] += dd * dd;
        }
    }
  }

  // reduce across the 16 col-lanes, then across waves
#pragma unroll
  for (int mt = 0; mt < 2; ++mt)
#pragma unroll
    for (int i = 0; i < 4; ++i) {
      float v = eacc[mt][i];
      v += __shfl_xor(v, 1, 16);
      v += __shfl_xor(v, 2, 16);
      v += __shfl_xor(v, 4, 16);
      v += __shfl_xor(v, 8, 16);
      if (lo == 0) errp[wv][mt * 16 + quad * 4 + i] = v;
    }
  __syncthreads();
  if (tid < 32)
    err[(size_t)k * NB + r0 + tid] =
        (errp[0][tid] + errp[1][tid] + errp[2][tid] + errp[3][tid]) * (1.0f / (float)ND);
}

// ---- argmin + bucket rows per expert
__global__ __launch_bounds__(256) void ae_argmin(const float* __restrict__ err,
                                                 unsigned int* __restrict__ cnt,
                                                 int* __restrict__ bucket) {
  __shared__ unsigned int lc[KE];
  __shared__ unsigned int base[KE];
  int tid = threadIdx.x;
  if (tid < KE) lc[tid] = 0;
  __syncthreads();
  int b = blockIdx.x * 256 + tid;
  float best = err[b];
  int kmin = 0;
#pragma unroll
  for (int j = 1; j < KE; ++j) {
    float e = err[(size_t)j * NB + b];
    if (e < best) { best = e; kmin = j; }   // strict < == first-min (jnp.argmin)
  }
  unsigned int lpos = atomicAdd(&lc[kmin], 1u);
  __syncthreads();
  if (tid < KE) base[tid] = atomicAdd(&cnt[tid], lc[tid]);
  __syncthreads();
  bucket[(size_t)kmin * NB + (int)(base[kmin] + lpos)] = b;
}

// ---- pass 2: recompute winner rows (plain bf16-hi), write f32 out
__global__ __launch_bounds__(256) void ae_pass2(
    const float* __restrict__ x,
    const unsigned short* __restrict__ w1h, const float* __restrict__ b1,
    const unsigned short* __restrict__ w2h, const float* __restrict__ b2,
    const unsigned int* __restrict__ cnt, const int* __restrict__ bucket,
    float* __restrict__ out) {
  __shared__ unsigned short hs[64][NH + 8];                  // 33792 B
  __shared__ union {
    struct { unsigned short xs[64][BK + 8]; unsigned short w1s[NH][BK + 8]; } a;
    struct { unsigned short w2ts[32][NH + 8]; } b;
  } u;
  __shared__ int rid[64];

  const int k = blockIdx.x & 7;
  const int cv = (int)cnt[k];
  const int t0 = (blockIdx.x >> 3) * 64;
  if (t0 >= cv) return;                     // uniform exit before any barrier
  const int nrows = min(64, cv - t0);

  const int tid = threadIdx.x;
  const int wv = tid >> 6;
  const int lane = tid & 63;
  const int lo = lane & 15;
  const int quad = lane >> 4;
  const int srow = tid >> 2, scol = (tid & 3) * 8;

  if (tid < 64) {
    int idx = t0 + tid;
    rid[tid] = bucket[(size_t)k * NB + (idx < cv ? idx : t0)];
  }
  __syncthreads();
  const int grow = rid[srow];

  f32x4 acc1[4][4];
#pragma unroll
  for (int mt = 0; mt < 4; ++mt)
#pragma unroll
    for (int nt = 0; nt < 4; ++nt) acc1[mt][nt] = (f32x4){0.f, 0.f, 0.f, 0.f};

  for (int kk = 0; kk < ND; kk += BK) {
    float4 xa = *(const float4*)&x[(size_t)grow * ND + kk + scol];
    float4 xb = *(const float4*)&x[(size_t)grow * ND + kk + scol + 4];
    __syncthreads();
    unsigned short t[8];
    t[0] = f2bf(xa.x); t[1] = f2bf(xa.y); t[2] = f2bf(xa.z); t[3] = f2bf(xa.w);
    t[4] = f2bf(xb.x); t[5] = f2bf(xb.y); t[6] = f2bf(xb.z); t[7] = f2bf(xb.w);
    *(u16x8*)&u.a.xs[srow][scol] = *(u16x8*)t;
#pragma unroll
    for (int p = 0; p < 4; ++p) {
      int j = p * 64 + srow;
      *(u16x8*)&u.a.w1s[j][scol] = *(const u16x8*)&w1h[((size_t)k * NH + j) * ND + kk + scol];
    }
    __syncthreads();
    s16x8 af[4], bfr[4];
#pragma unroll
    for (int mt = 0; mt < 4; ++mt) af[mt] = *(const s16x8*)&u.a.xs[mt * 16 + lo][quad * 8];
#pragma unroll
    for (int nt = 0; nt < 4; ++nt)
      bfr[nt] = *(const s16x8*)&u.a.w1s[wv * 64 + nt * 16 + lo][quad * 8];
#pragma unroll
    for (int mt = 0; mt < 4; ++mt)
#pragma unroll
      for (int nt = 0; nt < 4; ++nt)
        acc1[mt][nt] = __builtin_amdgcn_mfma_f32_16x16x32_bf16(af[mt], bfr[nt], acc1[mt][nt], 0, 0, 0);
  }
  __syncthreads();

#pragma unroll
  for (int nt = 0; nt < 4; ++nt) {
    float b1v = b1[(size_t)k * NH + wv * 64 + nt * 16 + lo];
#pragma unroll
    for (int mt = 0; mt < 4; ++mt)
#pragma unroll
      for (int i = 0; i < 4; ++i) {
        float v = acc1[mt][nt][i] + b1v;
        v = v > 0.f ? v : 0.f;
        hs[mt * 16 + quad * 4 + i][wv * 64 + nt * 16 + lo] = f2bf(v);
      }
  }
  __syncthreads();

  for (int c = 0; c < ND / 32; ++c) {
    const int d2b = c * 32;
#pragma unroll
    for (int p = 0; p < 4; ++p) {
      int d2 = p * 8 + (tid >> 5);
      int jc = (tid & 31) * 8;
      *(u16x8*)&u.b.w2ts[d2][jc] = *(const u16x8*)&w2h[((size_t)k * ND + d2b + d2) * NH + jc];
    }
    __syncthreads();

    f32x4 acc2[2];
    acc2[0] = (f32x4){0.f, 0.f, 0.f, 0.f};
    acc2[1] = (f32x4){0.f, 0.f, 0.f, 0.f};
#pragma unroll
    for (int kc = 0; kc < NH; kc += 32) {
      s16x8 af = *(const s16x8*)&hs[wv * 16 + lo][kc + quad * 8];
#pragma unroll
      for (int nt = 0; nt < 2; ++nt) {
        s16x8 bfr = *(const s16x8*)&u.b.w2ts[nt * 16 + lo][kc + quad * 8];
        acc2[nt] = __builtin_amdgcn_mfma_f32_16x16x32_bf16(af, bfr, acc2[nt], 0, 0, 0);
      }
    }
#pragma unroll
    for (int nt = 0; nt < 2; ++nt) {
      float b2v = b2[(size_t)k * ND + d2b + nt * 16 + lo];
#pragma unroll
      for (int i = 0; i < 4; ++i) {
        int row = wv * 16 + quad * 4 + i;
        if (row < nrows)
          out[(size_t)rid[row] * ND + d2b + nt * 16 + lo] = acc2[nt][i] + b2v;
      }
    }
    __syncthreads();
  }
}

extern "C" void kernel_launch(void* const* d_in, const int* in_sizes, int n_in,
                              void* d_out, int out_size, void* d_ws, size_t ws_size,
                              hipStream_t stream) {
  (void)in_sizes; (void)n_in; (void)out_size; (void)ws_size;
  const float* x  = (const float*)d_in[0];
  const float* W1 = (const float*)d_in[1];
  const float* b1 = (const float*)d_in[2];
  const float* W2 = (const float*)d_in[3];
  const float* b2 = (const float*)d_in[4];
  float* out = (float*)d_out;

  char* ws = (char*)d_ws;
  const size_t szW = (size_t)KE * ND * NH * sizeof(unsigned short);  // 4 MB
  unsigned short* w1h = (unsigned short*)(ws);
  unsigned short* w1l = (unsigned short*)(ws + szW);
  unsigned short* w2h = (unsigned short*)(ws + 2 * szW);
  unsigned short* w2l = (unsigned short*)(ws + 3 * szW);
  float* err          = (float*)(ws + 4 * szW);
  int* bucket         = (int*)(ws + 4 * szW + (size_t)KE * NB * sizeof(float));
  unsigned int* cnt   = (unsigned int*)(ws + 4 * szW + (size_t)KE * NB * sizeof(float)
                                        + (size_t)KE * NB * sizeof(int));
  // ws use ~17.3 MB

  split_w1<<<1024, 256, 0, stream>>>(W1, w1h, w1l);
  split_w2<<<1024, 256, 0, stream>>>(W2, w2h, w2l);
  ae_pass1<<<2048, 256, 0, stream>>>(x, w1h, w1l, b1, w2h, w2l, b2, err);
  hipMemsetAsync(cnt, 0, KE * sizeof(unsigned int), stream);
  ae_argmin<<<NB / 256, 256, 0, stream>>>(err, cnt, bucket);
  ae_pass2<<<1024, 256, 0, stream>>>(x, w1h, b1, w2h, b2, cnt, bucket, out);
}